// Round 1
// baseline (52.480 us; speedup 1.0000x reference)
//
#include <hip/hip_runtime.h>

#define PLACEHOLDER (-1)
#define TINY_F 1.17549435e-38f

__device__ __forceinline__ void amax_combine(float& bv, int& bi, float v, int i) {
    // jnp.argmax semantics: first occurrence wins ties -> prefer smaller index on equal
    if (v > bv || (v == bv && i < bi)) { bv = v; bi = i; }
}

__device__ __forceinline__ void block_argmax(float& bv, int& bi) {
    // wave (64-lane) butterfly-style down reduce
    for (int off = 32; off > 0; off >>= 1) {
        float ov = __shfl_down(bv, off, 64);
        int   oi = __shfl_down(bi, off, 64);
        amax_combine(bv, bi, ov, oi);
    }
    __shared__ float sv[8];
    __shared__ int   si[8];
    int lane = threadIdx.x & 63;
    int w    = threadIdx.x >> 6;
    if (lane == 0) { sv[w] = bv; si[w] = bi; }
    __syncthreads();
    if (threadIdx.x == 0) {
        int nw = (blockDim.x + 63) >> 6;
        for (int k = 1; k < nw; ++k) amax_combine(bv, bi, sv[k], si[k]);
    }
}

// Kernel A: target_argmax[b,p] for greedy rows at valid positions.
__global__ void k_argmax_greedy(const float* __restrict__ target_probs,
                                const int* __restrict__ draft_ids,
                                const int* __restrict__ is_greedy,
                                int* __restrict__ ws_argmax,
                                int B, int S, int V) {
    int bp = blockIdx.x;
    int b = bp / S, p = bp - b * S;
    if (!is_greedy[b]) return;
    if (draft_ids[bp] == PLACEHOLDER) return;

    const float* row = target_probs + (size_t)b * (S + 1) * V + (size_t)p * V;
    float bv = -1.0f; int bi = 0x7fffffff;
    int nv4 = V >> 2;
    const float4* r4 = (const float4*)row;
    for (int j = threadIdx.x; j < nv4; j += blockDim.x) {
        float4 f = r4[j];
        int base = j << 2;
        amax_combine(bv, bi, f.x, base);
        amax_combine(bv, bi, f.y, base + 1);
        amax_combine(bv, bi, f.z, base + 2);
        amax_combine(bv, bi, f.w, base + 3);
    }
    for (int j = (nv4 << 2) + threadIdx.x; j < V; j += blockDim.x)
        amax_combine(bv, bi, row[j], j);

    block_argmax(bv, bi);
    if (threadIdx.x == 0) ws_argmax[bp] = bi;
}

// Kernel B: per-row sequential accept/emit scan. One thread per batch row.
__global__ void k_decide(const int* __restrict__ draft_ids,
                         const float* __restrict__ draft_probs,
                         const float* __restrict__ target_probs,
                         const int* __restrict__ bonus,
                         const float* __restrict__ uniform,
                         const int* __restrict__ is_greedy,
                         const int* __restrict__ ws_argmax,
                         int* __restrict__ ws_fr,
                         int* __restrict__ out,
                         int B, int S, int V) {
    int b = blockIdx.x * blockDim.x + threadIdx.x;
    if (b >= B) return;
    bool greedy = is_greedy[b] != 0;
    int ng = 0;
    bool rejected = false;
    int fr = -1;                      // first-reject pos needing `recovered` (non-greedy only)
    int ob = b * (S + 1);

    for (int p = 0; p < S; ++p) {
        int tok = draft_ids[b * S + p];
        if (tok == PLACEHOLDER) break;   // valid is a contiguous prefix
        bool acc;
        int tout;
        if (greedy) {
            int am = ws_argmax[b * S + p];
            acc = (tok == am);
            tout = acc ? tok : am;       // replacement == target_argmax for greedy
        } else {
            float tp = target_probs[(size_t)b * (S + 1) * V + (size_t)p * V + tok];
            float dp = draft_probs[(size_t)b * S * V + (size_t)p * V + tok];
            acc = (tp / dp) >= uniform[b * S + p];
            tout = tok;                  // overwritten by kernel C if rejected
        }
        out[ob + p] = tout;
        ++ng;
        if (!acc) { rejected = true; if (!greedy) fr = p; break; }
    }
    for (int p = ng; p <= S; ++p) out[ob + p] = PLACEHOLDER;
    if (!rejected) out[ob + ng] = bonus[b];  // rejected -> slot stays PLACEHOLDER
    ws_fr[b] = fr;
}

// Kernel C: recovered = argmax( clip(t - d, TINY) / exp_q ) at the one position that needs it.
__global__ void k_recovered(const float* __restrict__ target_probs,
                            const float* __restrict__ draft_probs,
                            const float* __restrict__ exp_q,
                            const int* __restrict__ ws_fr,
                            int* __restrict__ out,
                            int B, int S, int V) {
    int b = blockIdx.x;
    int fr = ws_fr[b];
    if (fr < 0) return;

    const float* trow = target_probs + (size_t)b * (S + 1) * V + (size_t)fr * V;
    const float* drow = draft_probs + (size_t)b * S * V + (size_t)fr * V;
    const float* erow = exp_q + (size_t)b * V;

    float bv = -1.0f; int bi = 0x7fffffff;
    int nv4 = V >> 2;
    const float4* t4 = (const float4*)trow;
    const float4* d4 = (const float4*)drow;
    const float4* e4 = (const float4*)erow;
    for (int j = threadIdx.x; j < nv4; j += blockDim.x) {
        float4 t = t4[j], d = d4[j], e = e4[j];
        int base = j << 2;
        amax_combine(bv, bi, fmaxf(t.x - d.x, TINY_F) / e.x, base);
        amax_combine(bv, bi, fmaxf(t.y - d.y, TINY_F) / e.y, base + 1);
        amax_combine(bv, bi, fmaxf(t.z - d.z, TINY_F) / e.z, base + 2);
        amax_combine(bv, bi, fmaxf(t.w - d.w, TINY_F) / e.w, base + 3);
    }
    for (int j = (nv4 << 2) + threadIdx.x; j < V; j += blockDim.x)
        amax_combine(bv, bi, fmaxf(trow[j] - drow[j], TINY_F) / erow[j], j);

    block_argmax(bv, bi);
    if (threadIdx.x == 0) out[b * (S + 1) + fr] = bi;
}

extern "C" void kernel_launch(void* const* d_in, const int* in_sizes, int n_in,
                              void* d_out, int out_size, void* d_ws, size_t ws_size,
                              hipStream_t stream) {
    const int*   draft_ids    = (const int*)d_in[0];
    const float* draft_probs  = (const float*)d_in[1];
    const float* target_probs = (const float*)d_in[2];
    const int*   bonus        = (const int*)d_in[3];
    const float* uniform      = (const float*)d_in[4];
    const float* exp_q        = (const float*)d_in[5];
    const int*   is_greedy    = (const int*)d_in[6];

    int B = in_sizes[6];           // 128
    int S = in_sizes[4] / B;       // 8
    int V = in_sizes[5] / B;       // 32000

    int* ws_argmax = (int*)d_ws;           // B*S ints
    int* ws_fr     = ws_argmax + B * S;    // B ints
    int* out       = (int*)d_out;

    k_argmax_greedy<<<B * S, 256, 0, stream>>>(target_probs, draft_ids, is_greedy,
                                               ws_argmax, B, S, V);
    k_decide<<<(B + 63) / 64, 64, 0, stream>>>(draft_ids, draft_probs, target_probs,
                                               bonus, uniform, is_greedy,
                                               ws_argmax, ws_fr, out, B, S, V);
    k_recovered<<<B, 256, 0, stream>>>(target_probs, draft_probs, exp_q,
                                       ws_fr, out, B, S, V);
}

// Round 2
// 34.869 us; speedup vs baseline: 1.5051x; 1.5051x over previous
//
#include <hip/hip_runtime.h>

#define PLACEHOLDER (-1)
#define TINY_F 1.17549435e-38f
#define MAXS 32
#define SPLIT_G 4
#define SPLIT_R 8

__device__ __forceinline__ void amax_combine(float& bv, int& bi, float v, int i) {
    // jnp.argmax: first occurrence wins ties -> prefer smaller index on equal value
    if (v > bv || (v == bv && i < bi)) { bv = v; bi = i; }
}

__device__ __forceinline__ unsigned long long pack_vi(float v, int i) {
    return ((unsigned long long)__float_as_uint(v) << 32) |
           (unsigned long long)(0xFFFFFFFFu - (unsigned)i);
}

__device__ __forceinline__ int unpack_idx(unsigned long long p) {
    return (int)(0xFFFFFFFFu - (unsigned)(p & 0xFFFFFFFFull));
}

// block-level argmax reduce; result valid on thread 0
__device__ __forceinline__ void block_argmax(float& bv, int& bi) {
    for (int off = 32; off > 0; off >>= 1) {
        float ov = __shfl_down(bv, off, 64);
        int   oi = __shfl_down(bi, off, 64);
        amax_combine(bv, bi, ov, oi);
    }
    __shared__ float sv[8];
    __shared__ int   si[8];
    int lane = threadIdx.x & 63;
    int w    = threadIdx.x >> 6;
    if (lane == 0) { sv[w] = bv; si[w] = bi; }
    __syncthreads();
    if (threadIdx.x == 0) {
        int nw = (blockDim.x + 63) >> 6;
        for (int k = 1; k < nw; ++k) amax_combine(bv, bi, sv[k], si[k]);
    }
}

// Kernel 1: zero packed-argmax ws; non-greedy rows: full accept scan + output row + fr.
__global__ void k_prep(const int* __restrict__ draft_ids,
                       const float* __restrict__ draft_probs,
                       const float* __restrict__ target_probs,
                       const int* __restrict__ bonus,
                       const float* __restrict__ uniform,
                       const int* __restrict__ is_greedy,
                       unsigned long long* __restrict__ ws_pk,   // B*S + B entries
                       int* __restrict__ ws_fr,
                       int* __restrict__ out,
                       int B, int S, int V) {
    int n_pk = B * S + B;
    for (int i = threadIdx.x; i < n_pk; i += blockDim.x) ws_pk[i] = 0ull;

    int b = threadIdx.x;
    if (b >= B) return;

    int toks[MAXS];
    int L = 0;
    for (int p = 0; p < S; ++p) {
        toks[p] = draft_ids[b * S + p];
        if (toks[p] == PLACEHOLDER && L == p) { /* first placeholder marks end */ }
    }
    while (L < S && toks[L] != PLACEHOLDER) ++L;

    if (is_greedy[b]) { ws_fr[b] = -1; return; }   // greedy rows handled by k_final

    // batched independent gathered loads for all valid positions
    float tp[MAXS], dp[MAXS], uu[MAXS];
    for (int p = 0; p < L; ++p) {
        tp[p] = target_probs[(size_t)b * (S + 1) * V + (size_t)p * V + toks[p]];
        dp[p] = draft_probs[(size_t)b * S * V + (size_t)p * V + toks[p]];
        uu[p] = uniform[b * S + p];
    }

    int ob = b * (S + 1);
    int ng = 0;
    bool rejected = false;
    int fr = -1;
    for (int p = 0; p < L; ++p) {
        bool acc = (tp[p] / dp[p]) >= uu[p];
        out[ob + p] = toks[p];            // reject position overwritten by k_final
        ++ng;
        if (!acc) { rejected = true; fr = p; break; }
    }
    for (int p = ng; p <= S; ++p) out[ob + p] = PLACEHOLDER;
    if (!rejected) out[ob + ng] = bonus[b];
    ws_fr[b] = fr;
}

// Kernel 2: all heavy argmax scans in one flat grid, merged via packed atomicMax.
//   blocks [0, B*S*SPLIT_G)         : greedy-row target argmax (chunk of V)
//   blocks [B*S*SPLIT_G, +B*SPLIT_R): recovered argmax (chunk of V, 3 arrays)
__global__ void k_main(const float* __restrict__ target_probs,
                       const float* __restrict__ draft_probs,
                       const float* __restrict__ exp_q,
                       const int* __restrict__ draft_ids,
                       const int* __restrict__ is_greedy,
                       const int* __restrict__ ws_fr,
                       unsigned long long* __restrict__ ws_pk,
                       int B, int S, int V) {
    int total_g = B * S * SPLIT_G;
    float bv = 0.0f; int bi = 0x7fffffff;
    unsigned long long* dst;

    if ((int)blockIdx.x < total_g) {
        int t = blockIdx.x;
        int split = t % SPLIT_G;
        int bp = t / SPLIT_G;
        int b = bp / S;
        if (!is_greedy[b]) return;
        if (draft_ids[bp] == PLACEHOLDER) return;
        int p = bp - b * S;

        int chunk = ((V + SPLIT_G - 1) / SPLIT_G + 3) & ~3;
        int begin = split * chunk;
        int end = begin + chunk; if (end > V) end = V;
        if (begin >= end) return;

        const float* row = target_probs + (size_t)b * (S + 1) * V + (size_t)p * V;
        int vend = begin + ((end - begin) & ~3);
        const float4* r4 = (const float4*)row;
        for (int j = (begin >> 2) + threadIdx.x; j < (vend >> 2); j += blockDim.x) {
            float4 f = r4[j];
            int base = j << 2;
            amax_combine(bv, bi, f.x, base);
            amax_combine(bv, bi, f.y, base + 1);
            amax_combine(bv, bi, f.z, base + 2);
            amax_combine(bv, bi, f.w, base + 3);
        }
        for (int j = vend + threadIdx.x; j < end; j += blockDim.x)
            amax_combine(bv, bi, row[j], j);
        dst = ws_pk + bp;
    } else {
        int t = blockIdx.x - total_g;
        int split = t % SPLIT_R;
        int b = t / SPLIT_R;
        int fr = ws_fr[b];
        if (fr < 0) return;

        int chunk = ((V + SPLIT_R - 1) / SPLIT_R + 3) & ~3;
        int begin = split * chunk;
        int end = begin + chunk; if (end > V) end = V;
        if (begin >= end) return;

        const float* trow = target_probs + (size_t)b * (S + 1) * V + (size_t)fr * V;
        const float* drow = draft_probs + (size_t)b * S * V + (size_t)fr * V;
        const float* erow = exp_q + (size_t)b * V;
        int vend = begin + ((end - begin) & ~3);
        const float4* t4 = (const float4*)trow;
        const float4* d4 = (const float4*)drow;
        const float4* e4 = (const float4*)erow;
        for (int j = (begin >> 2) + threadIdx.x; j < (vend >> 2); j += blockDim.x) {
            float4 tt = t4[j], dd = d4[j], ee = e4[j];
            int base = j << 2;
            amax_combine(bv, bi, fmaxf(tt.x - dd.x, TINY_F) / ee.x, base);
            amax_combine(bv, bi, fmaxf(tt.y - dd.y, TINY_F) / ee.y, base + 1);
            amax_combine(bv, bi, fmaxf(tt.z - dd.z, TINY_F) / ee.z, base + 2);
            amax_combine(bv, bi, fmaxf(tt.w - dd.w, TINY_F) / ee.w, base + 3);
        }
        for (int j = vend + threadIdx.x; j < end; j += blockDim.x)
            amax_combine(bv, bi, fmaxf(trow[j] - drow[j], TINY_F) / erow[j], j);
        dst = ws_pk + B * S + b;
    }

    block_argmax(bv, bi);
    if (threadIdx.x == 0 && bi != 0x7fffffff)
        atomicMax(dst, pack_vi(bv, bi));
}

// Kernel 3: greedy rows full output; non-greedy rows patch recovered token at fr.
__global__ void k_final(const int* __restrict__ draft_ids,
                        const int* __restrict__ bonus,
                        const int* __restrict__ is_greedy,
                        const unsigned long long* __restrict__ ws_pk,
                        const int* __restrict__ ws_fr,
                        int* __restrict__ out,
                        int B, int S, int V) {
    int b = threadIdx.x;
    if (b >= B) return;
    int ob = b * (S + 1);

    if (is_greedy[b]) {
        int ng = 0;
        bool rejected = false;
        for (int p = 0; p < S; ++p) {
            int tok = draft_ids[b * S + p];
            if (tok == PLACEHOLDER) break;
            int am = unpack_idx(ws_pk[b * S + p]);
            bool acc = (tok == am);
            out[ob + p] = acc ? tok : am;
            ++ng;
            if (!acc) { rejected = true; break; }
        }
        for (int p = ng; p <= S; ++p) out[ob + p] = PLACEHOLDER;
        if (!rejected) out[ob + ng] = bonus[b];
    } else {
        int fr = ws_fr[b];
        if (fr >= 0) out[ob + fr] = unpack_idx(ws_pk[B * S + b]);
    }
}

extern "C" void kernel_launch(void* const* d_in, const int* in_sizes, int n_in,
                              void* d_out, int out_size, void* d_ws, size_t ws_size,
                              hipStream_t stream) {
    const int*   draft_ids    = (const int*)d_in[0];
    const float* draft_probs  = (const float*)d_in[1];
    const float* target_probs = (const float*)d_in[2];
    const int*   bonus        = (const int*)d_in[3];
    const float* uniform      = (const float*)d_in[4];
    const float* exp_q        = (const float*)d_in[5];
    const int*   is_greedy    = (const int*)d_in[6];

    int B = in_sizes[6];           // 128
    int S = in_sizes[4] / B;       // 8
    int V = in_sizes[5] / B;       // 32000

    unsigned long long* ws_pk = (unsigned long long*)d_ws;   // B*S + B
    int* ws_fr = (int*)(ws_pk + B * S + B);                  // B
    int* out   = (int*)d_out;

    k_prep<<<1, 256, 0, stream>>>(draft_ids, draft_probs, target_probs, bonus,
                                  uniform, is_greedy, ws_pk, ws_fr, out, B, S, V);
    int grid = B * S * SPLIT_G + B * SPLIT_R;
    k_main<<<grid, 256, 0, stream>>>(target_probs, draft_probs, exp_q, draft_ids,
                                     is_greedy, ws_fr, ws_pk, B, S, V);
    k_final<<<1, B, 0, stream>>>(draft_ids, bonus, is_greedy, ws_pk, ws_fr,
                                 out, B, S, V);
}